// Round 3
// baseline (1440.693 us; speedup 1.0000x reference)
//
#include <hip/hip_runtime.h>

// LatentDynamicsModel fused: in-proj + GRU cell + out-proj.
// I/O fp32; internal math bf16 MFMA + fp32 accum (threshold 9.94e-2 allows it).
// Round 2: BM=64 rows/block, 512 threads (8 waves x 32 output cols),
// hid/z pre-converted to bf16 in prep (no inline cvt tax), occupancy 16 waves/CU.

typedef unsigned short u16;
typedef unsigned int u32;
using bf16x8 = __attribute__((ext_vector_type(8))) short;  // 8 bf16 (4 VGPRs)
using f32x4  = __attribute__((ext_vector_type(4))) float;  // 4 fp32 acc

constexpr int B_TOT = 131072;
constexpr int BM    = 64;    // batch rows per block
constexpr int SX    = 264;   // LDS row stride (256 + 8 pad)

// d_ws layout (u16 elements)
constexpr size_t OFF_WIN = 0;         // W_in padded: 256 x 72
constexpr size_t OFF_WIH = 18432;     // 768 x 256
constexpr size_t OFF_WHH = 215040;    // 768 x 256
constexpr size_t OFF_WO1 = 411648;    // 256 x 256
constexpr size_t OFF_WO2 = 477184;    // 64 x 256
constexpr size_t OFF_ZB  = 493568;    // z bf16: 131072 x 64
constexpr size_t OFF_HB  = 8882176;   // hid bf16: 131072 x 256
constexpr size_t WS_W_TOT = 493568;   // weight-prep element count

__device__ __forceinline__ u16 f2b(float f) {  // RNE float->bf16
    u32 u = __builtin_bit_cast(u32, f);
    return (u16)((u + 0x7FFFu + ((u >> 16) & 1u)) >> 16);
}
__device__ __forceinline__ float b2f(u16 u) {
    u32 x = (u32)u << 16;
    return __builtin_bit_cast(float, x);
}
__device__ __forceinline__ float sigm(float x) {
    x = fminf(fmaxf(x, -30.f), 30.f);
    float e = __expf(x);
    return e * __builtin_amdgcn_rcpf(1.f + e);
}
__device__ __forceinline__ float tanh_(float x) {
    x = fminf(fmaxf(x, -15.f), 15.f);
    float e = __expf(2.f * x);
    return (e - 1.f) * __builtin_amdgcn_rcpf(e + 1.f);
}

#define MFMA(a, b, c) __builtin_amdgcn_mfma_f32_16x16x32_bf16((a), (b), (c), 0, 0, 0)

// ---------- prep 1: weights fp32 -> bf16 ----------
__global__ void prep_weights(const float* __restrict__ W_in, const float* __restrict__ W_ih,
                             const float* __restrict__ W_hh, const float* __restrict__ W_o1,
                             const float* __restrict__ W_o2, u16* __restrict__ ws)
{
    size_t i = (size_t)blockIdx.x * blockDim.x + threadIdx.x;
    if (i >= WS_W_TOT) return;
    if (i < OFF_WIH) {                       // W_in padded to stride 72
        size_t r = i / 72, c = i - r * 72;
        ws[i] = (c < 66) ? f2b(W_in[r * 66 + c]) : (u16)0;
    } else if (i < OFF_WHH) {
        ws[i] = f2b(W_ih[i - OFF_WIH]);
    } else if (i < OFF_WO1) {
        ws[i] = f2b(W_hh[i - OFF_WHH]);
    } else if (i < OFF_WO2) {
        ws[i] = f2b(W_o1[i - OFF_WO1]);
    } else {
        ws[i] = f2b(W_o2[i - OFF_WO2]);
    }
}

// ---------- prep 2: fp32 array -> bf16 (n4 = count/4) ----------
__global__ void prep_cast(const float* __restrict__ src, u16* __restrict__ dst, int n4)
{
    int i = blockIdx.x * blockDim.x + threadIdx.x;
    if (i >= n4) return;
    float4 v = reinterpret_cast<const float4*>(src)[i];
    ushort4 o;
    o.x = f2b(v.x); o.y = f2b(v.y); o.z = f2b(v.z); o.w = f2b(v.w);
    reinterpret_cast<ushort4*>(dst)[i] = o;
}

// ---------- main fused kernel ----------
__global__ __launch_bounds__(512, 4)
void ldm_fused(const float* __restrict__ act,
               const float* __restrict__ W_in_f, const float* __restrict__ b_in,
               const float* __restrict__ b_ih, const float* __restrict__ b_hh,
               const float* __restrict__ b_o1, const float* __restrict__ b_o2,
               const u16* __restrict__ ws,
               float* __restrict__ zn_out, float* __restrict__ h_out)
{
    __shared__ u16 xbuf[BM * SX];   // x (bf16), later reused for y
    __shared__ u16 hnew[BM * SX];   // h_new (bf16)

    const int tid  = threadIdx.x;
    const int w    = tid >> 6;      // wave 0..7
    const int lane = tid & 63;
    const int l16  = lane & 15;
    const int quad = lane >> 4;
    const int row0 = blockIdx.x * BM;

    const u16* Wib = ws + OFF_WIN;   // padded stride 72
    const u16* Wih = ws + OFF_WIH;
    const u16* Whh = ws + OFF_WHH;
    const u16* Wo1 = ws + OFF_WO1;
    const u16* Wo2 = ws + OFF_WO2;
    const u16* zb  = ws + OFF_ZB + (size_t)row0 * 64;    // block's z tile (bf16)
    const u16* hb  = ws + OFF_HB + (size_t)row0 * 256;   // block's hid tile (bf16)

    // ================= Stage A: x = relu([z|action] @ W_in^T + b_in) =================
    {
        bf16x8 az[4][2];  // [m-tile][k-chunk]
        #pragma unroll
        for (int mt = 0; mt < 4; ++mt) {
            const u16* zp = zb + (mt * 16 + l16) * 64 + quad * 8;
            az[mt][0] = *reinterpret_cast<const bf16x8*>(zp);
            az[mt][1] = *reinterpret_cast<const bf16x8*>(zp + 32);
        }
        #pragma unroll
        for (int ot = 0; ot < 2; ++ot) {
            const int orow = w * 32 + ot * 16 + l16;  // output col / W_in row
            bf16x8 bw[2];
            #pragma unroll
            for (int kc = 0; kc < 2; ++kc)
                bw[kc] = *reinterpret_cast<const bf16x8*>(Wib + orow * 72 + kc * 32 + quad * 8);
            f32x4 acc[4];
            #pragma unroll
            for (int mt = 0; mt < 4; ++mt) acc[mt] = {0.f, 0.f, 0.f, 0.f};
            #pragma unroll
            for (int kc = 0; kc < 2; ++kc)
                #pragma unroll
                for (int mt = 0; mt < 4; ++mt)
                    acc[mt] = MFMA(az[mt][kc], bw[kc], acc[mt]);
            // epilogue: + action outer product + bias, relu -> LDS (bf16)
            const float w64v = W_in_f[orow * 66 + 64];
            const float w65v = W_in_f[orow * 66 + 65];
            const float bi   = b_in[orow];
            #pragma unroll
            for (int mt = 0; mt < 4; ++mt) {
                #pragma unroll
                for (int i = 0; i < 4; ++i) {
                    const int rl = mt * 16 + quad * 4 + i;   // local row (C/D layout)
                    const float2 av = reinterpret_cast<const float2*>(act)[row0 + rl];
                    float v = acc[mt][i] + av.x * w64v + av.y * w65v + bi;
                    xbuf[rl * SX + orow] = f2b(fmaxf(v, 0.f));
                }
            }
        }
    }
    __syncthreads();

    // ================= Stage B: GRU gates =================
    // Each wave: 32 output cols, in 2 half-groups of 16 to cap acc VGPRs at 64.
    #pragma unroll 1
    for (int hf = 0; hf < 2; ++hf) {
        const int r0 = w * 32 + hf * 16 + l16;   // output col / gate row
        f32x4 aR[4], aZ[4], aNi[4], aNh[4];
        #pragma unroll
        for (int mt = 0; mt < 4; ++mt) {
            aR[mt]  = {0.f, 0.f, 0.f, 0.f};
            aZ[mt]  = {0.f, 0.f, 0.f, 0.f};
            aNi[mt] = {0.f, 0.f, 0.f, 0.f};
            aNh[mt] = {0.f, 0.f, 0.f, 0.f};
        }
        // phase X: K over x (A-frags from LDS)
        #pragma unroll
        for (int kc = 0; kc < 8; ++kc) {
            const int ko = kc * 32 + quad * 8;
            bf16x8 ax[4];
            #pragma unroll
            for (int mt = 0; mt < 4; ++mt)
                ax[mt] = *reinterpret_cast<const bf16x8*>(&xbuf[(mt * 16 + l16) * SX + ko]);
            const bf16x8 br_ = *reinterpret_cast<const bf16x8*>(Wih + (size_t)r0 * 256 + ko);
            const bf16x8 bz_ = *reinterpret_cast<const bf16x8*>(Wih + (size_t)(r0 + 256) * 256 + ko);
            const bf16x8 bn_ = *reinterpret_cast<const bf16x8*>(Wih + (size_t)(r0 + 512) * 256 + ko);
            #pragma unroll
            for (int mt = 0; mt < 4; ++mt) {
                aR[mt]  = MFMA(ax[mt], br_, aR[mt]);
                aZ[mt]  = MFMA(ax[mt], bz_, aZ[mt]);
                aNi[mt] = MFMA(ax[mt], bn_, aNi[mt]);
            }
        }
        // phase H: K over h (A-frags from bf16 hid tile in global, L1/L2-hot)
        #pragma unroll
        for (int kc = 0; kc < 8; ++kc) {
            const int ko = kc * 32 + quad * 8;
            bf16x8 ah[4];
            #pragma unroll
            for (int mt = 0; mt < 4; ++mt)
                ah[mt] = *reinterpret_cast<const bf16x8*>(hb + (mt * 16 + l16) * 256 + ko);
            const bf16x8 br_ = *reinterpret_cast<const bf16x8*>(Whh + (size_t)r0 * 256 + ko);
            const bf16x8 bz_ = *reinterpret_cast<const bf16x8*>(Whh + (size_t)(r0 + 256) * 256 + ko);
            const bf16x8 bn_ = *reinterpret_cast<const bf16x8*>(Whh + (size_t)(r0 + 512) * 256 + ko);
            #pragma unroll
            for (int mt = 0; mt < 4; ++mt) {
                aR[mt]  = MFMA(ah[mt], br_, aR[mt]);
                aZ[mt]  = MFMA(ah[mt], bz_, aZ[mt]);
                aNh[mt] = MFMA(ah[mt], bn_, aNh[mt]);
            }
        }
        // gate epilogue
        {
            const int o = r0;
            const float br_b = b_ih[o]       + b_hh[o];
            const float bz_b = b_ih[o + 256] + b_hh[o + 256];
            const float bni  = b_ih[o + 512];
            const float bnh  = b_hh[o + 512];
            #pragma unroll
            for (int mt = 0; mt < 4; ++mt) {
                #pragma unroll
                for (int i = 0; i < 4; ++i) {
                    const int rl = mt * 16 + quad * 4 + i;
                    const float hv = b2f(hb[rl * 256 + o]);
                    const float r  = sigm(aR[mt][i] + br_b);
                    const float zg = sigm(aZ[mt][i] + bz_b);
                    const float n  = tanh_(aNi[mt][i] + bni + r * (aNh[mt][i] + bnh));
                    const float hn = n + zg * (hv - n);   // (1-zg)*n + zg*h
                    hnew[rl * SX + o] = f2b(hn);
                }
            }
        }
    }
    __syncthreads();

    // coalesced h_new -> global fp32 (each thread 4 x 8 elements)
    #pragma unroll
    for (int it = 0; it < 4; ++it) {
        const int idx = it * 4096 + tid * 8;
        const int r = idx >> 8, c = idx & 255;
        const bf16x8 v = *reinterpret_cast<const bf16x8*>(&hnew[r * SX + c]);
        float4 f0, f1;
        f0.x = b2f((u16)v[0]); f0.y = b2f((u16)v[1]); f0.z = b2f((u16)v[2]); f0.w = b2f((u16)v[3]);
        f1.x = b2f((u16)v[4]); f1.y = b2f((u16)v[5]); f1.z = b2f((u16)v[6]); f1.w = b2f((u16)v[7]);
        float* dst = h_out + (size_t)(row0 + r) * 256 + c;
        *reinterpret_cast<float4*>(dst)     = f0;
        *reinterpret_cast<float4*>(dst + 4) = f1;
    }

    // ================= Stage 4: y = relu(h_new @ W_o1^T + b_o1) -> xbuf =================
    {
        f32x4 aY[2][4];
        #pragma unroll
        for (int ot = 0; ot < 2; ++ot)
            #pragma unroll
            for (int mt = 0; mt < 4; ++mt) aY[ot][mt] = {0.f, 0.f, 0.f, 0.f};
        #pragma unroll
        for (int kc = 0; kc < 8; ++kc) {
            const int ko = kc * 32 + quad * 8;
            bf16x8 ah2[4];
            #pragma unroll
            for (int mt = 0; mt < 4; ++mt)
                ah2[mt] = *reinterpret_cast<const bf16x8*>(&hnew[(mt * 16 + l16) * SX + ko]);
            #pragma unroll
            for (int ot = 0; ot < 2; ++ot) {
                const bf16x8 bo = *reinterpret_cast<const bf16x8*>(
                    Wo1 + (size_t)(w * 32 + ot * 16 + l16) * 256 + ko);
                #pragma unroll
                for (int mt = 0; mt < 4; ++mt)
                    aY[ot][mt] = MFMA(ah2[mt], bo, aY[ot][mt]);
            }
        }
        #pragma unroll
        for (int ot = 0; ot < 2; ++ot) {
            const int o = w * 32 + ot * 16 + l16;
            const float bo1 = b_o1[o];
            #pragma unroll
            for (int mt = 0; mt < 4; ++mt)
                #pragma unroll
                for (int i = 0; i < 4; ++i) {
                    const int rl = mt * 16 + quad * 4 + i;
                    xbuf[rl * SX + o] = f2b(fmaxf(aY[ot][mt][i] + bo1, 0.f));
                }
        }
    }
    __syncthreads();

    // ================= Stage 5: z_next = y @ W_o2^T + b_o2 =================
    // 8 waves: col group (w&3)*16, row half (w>>2)*32.
    {
        const int c0 = (w & 3) * 16;
        const int mh = w >> 2;
        f32x4 aO[2];
        aO[0] = {0.f, 0.f, 0.f, 0.f};
        aO[1] = {0.f, 0.f, 0.f, 0.f};
        #pragma unroll
        for (int kc = 0; kc < 8; ++kc) {
            const int ko = kc * 32 + quad * 8;
            const bf16x8 bo2 = *reinterpret_cast<const bf16x8*>(Wo2 + (size_t)(c0 + l16) * 256 + ko);
            #pragma unroll
            for (int mm = 0; mm < 2; ++mm) {
                const bf16x8 ay = *reinterpret_cast<const bf16x8*>(
                    &xbuf[((mh * 2 + mm) * 16 + l16) * SX + ko]);
                aO[mm] = MFMA(ay, bo2, aO[mm]);
            }
        }
        const int o = c0 + l16;
        const float bz2 = b_o2[o];
        #pragma unroll
        for (int mm = 0; mm < 2; ++mm)
            #pragma unroll
            for (int i = 0; i < 4; ++i) {
                const int rl = (mh * 2 + mm) * 16 + quad * 4 + i;
                zn_out[(size_t)(row0 + rl) * 64 + o] = aO[mm][i] + bz2;
            }
    }
}

extern "C" void kernel_launch(void* const* d_in, const int* in_sizes, int n_in,
                              void* d_out, int out_size, void* d_ws, size_t ws_size,
                              hipStream_t stream) {
    const float* z    = (const float*)d_in[0];
    const float* act  = (const float*)d_in[1];
    const float* hid  = (const float*)d_in[2];
    const float* W_in = (const float*)d_in[3];
    const float* b_in = (const float*)d_in[4];
    const float* W_ih = (const float*)d_in[5];
    const float* W_hh = (const float*)d_in[6];
    const float* b_ih = (const float*)d_in[7];
    const float* b_hh = (const float*)d_in[8];
    const float* W_o1 = (const float*)d_in[9];
    const float* b_o1 = (const float*)d_in[10];
    const float* W_o2 = (const float*)d_in[11];
    const float* b_o2 = (const float*)d_in[12];

    u16* ws = (u16*)d_ws;

    float* zn_out = (float*)d_out;                      // [B, 64]
    float* h_out  = zn_out + (size_t)B_TOT * 64;        // [1, B, 256]

    prep_weights<<<dim3((WS_W_TOT + 255) / 256), dim3(256), 0, stream>>>(
        W_in, W_ih, W_hh, W_o1, W_o2, ws);
    prep_cast<<<dim3((B_TOT * 64 / 4 + 255) / 256), dim3(256), 0, stream>>>(
        z, ws + OFF_ZB, B_TOT * 64 / 4);
    prep_cast<<<dim3((B_TOT * 256 / 4 + 255) / 256), dim3(256), 0, stream>>>(
        hid, ws + OFF_HB, B_TOT * 256 / 4);

    ldm_fused<<<dim3(B_TOT / BM), dim3(512), 0, stream>>>(
        act, W_in, b_in, b_ih, b_hh, b_o1, b_o2, ws, zn_out, h_out);
}

// Round 4
// 1111.400 us; speedup vs baseline: 1.2963x; 1.2963x over previous
//
#include <hip/hip_runtime.h>

// LatentDynamicsModel fused, round 3: weight-stationary design.
// One block = 1024 threads = 16 waves; wave w owns output cols [w*16, w*16+16).
// ALL weight B-fragments live in registers for the whole kernel (~268 VGPR);
// activations staged per-tile into padded LDS (fp32->bf16 cast amortized).
// Inner loops: ds_read_b128 + MFMA only -> no global latency in MFMA chains.
// Grid 512 blocks x 8 tiles of 32 rows = 131072 rows.

typedef unsigned short u16;
typedef unsigned int u32;
using bf16x8 = __attribute__((ext_vector_type(8))) short;  // 8 bf16 (4 VGPRs)
using f32x4  = __attribute__((ext_vector_type(4))) float;  // 4 fp32 acc

constexpr int B_TOT = 131072;

// ws layout (u16 elements) — weights only (~1 MB, L2-resident)
constexpr size_t OFF_WIB = 0;        // 256 x 96  ([z|act|0] padded K=96)
constexpr size_t OFF_WIH = 24576;    // 768 x 256
constexpr size_t OFF_WHH = 221184;   // 768 x 256
constexpr size_t OFF_WO1 = 417792;   // 256 x 256
constexpr size_t OFF_WO2 = 483328;   // 64 x 256
constexpr size_t WS_TOT  = 499712;

// LDS strides (elements): 264 = 256+8 pad, 104 = 96+8 pad -> 2-way bank alias (free)
constexpr int SH = 264;
constexpr int SZ = 104;

__device__ __forceinline__ u16 f2b(float f) {  // RNE float->bf16
    u32 u = __builtin_bit_cast(u32, f);
    return (u16)((u + 0x7FFFu + ((u >> 16) & 1u)) >> 16);
}
__device__ __forceinline__ float b2f(u16 u) {
    u32 x = (u32)u << 16;
    return __builtin_bit_cast(float, x);
}
__device__ __forceinline__ float sigm(float x) {
    x = fminf(fmaxf(x, -30.f), 30.f);
    float e = __expf(x);
    return e * __builtin_amdgcn_rcpf(1.f + e);
}
__device__ __forceinline__ float tanh_(float x) {
    x = fminf(fmaxf(x, -15.f), 15.f);
    float e = __expf(2.f * x);
    return (e - 1.f) * __builtin_amdgcn_rcpf(e + 1.f);
}

#define MFMA(a, b, c) __builtin_amdgcn_mfma_f32_16x16x32_bf16((a), (b), (c), 0, 0, 0)
#define ZERO4 f32x4{0.f, 0.f, 0.f, 0.f}

// ---------- prep: weights fp32 -> bf16 into ws ----------
__global__ void prep_weights(const float* __restrict__ W_in, const float* __restrict__ W_ih,
                             const float* __restrict__ W_hh, const float* __restrict__ W_o1,
                             const float* __restrict__ W_o2, u16* __restrict__ ws)
{
    size_t i = (size_t)blockIdx.x * blockDim.x + threadIdx.x;
    if (i >= WS_TOT) return;
    if (i < OFF_WIH) {                       // W_in padded to K=96 (cols 66..95 = 0)
        size_t r = i / 96, c = i - r * 96;
        ws[i] = (c < 66) ? f2b(W_in[r * 66 + c]) : (u16)0;
    } else if (i < OFF_WHH) {
        ws[i] = f2b(W_ih[i - OFF_WIH]);
    } else if (i < OFF_WO1) {
        ws[i] = f2b(W_hh[i - OFF_WHH]);
    } else if (i < OFF_WO2) {
        ws[i] = f2b(W_o1[i - OFF_WO1]);
    } else {
        ws[i] = f2b(W_o2[i - OFF_WO2]);
    }
}

// ---------- main fused kernel ----------
__global__ __launch_bounds__(1024)
void ldm_fused(const float* __restrict__ z, const float* __restrict__ act,
               const float* __restrict__ hid,
               const float* __restrict__ b_in, const float* __restrict__ b_ih,
               const float* __restrict__ b_hh, const float* __restrict__ b_o1,
               const float* __restrict__ b_o2,
               const u16* __restrict__ ws,
               float* __restrict__ zn_out, float* __restrict__ h_out)
{
    __shared__ u16 zb[32 * SZ];     // [z|act|0] tile, bf16, K=96 padded
    __shared__ u16 hb[32 * SH];     // hid tile bf16
    __shared__ u16 xbuf[32 * SH];   // x = stage-A output
    __shared__ u16 hnew[32 * SH];   // h_new
    __shared__ u16 ybuf[32 * SH];   // y = stage-4 output

    const int tid  = threadIdx.x;
    const int w    = tid >> 6;      // wave 0..15
    const int lane = tid & 63;
    const int l16  = lane & 15;
    const int quad = lane >> 4;
    const int o    = w * 16 + l16;  // this wave's output col (0..255)

    // staging coordinates (shared by hid-load and h_out-store)
    const int sr = tid >> 5;            // row 0..31
    const int sc = (tid & 31) * 8;      // col 0..248 step 8

    // ---- hoisted biases (wave-constant per lane) ----
    const float bin_ = b_in[o];
    const float brb  = b_ih[o]       + b_hh[o];
    const float bzb  = b_ih[o + 256] + b_hh[o + 256];
    const float bni  = b_ih[o + 512];
    const float bnh  = b_hh[o + 512];
    const float bo1_ = b_o1[o];
    const int   cg   = w & 3, mh = w >> 2;   // stage-5 mapping (waves 0..7 active)
    const int   o5   = cg * 16 + l16;        // 0..63
    const float bo2_ = b_o2[o5];

    // ---- preload ALL weight fragments into registers (persistent) ----
    const u16* Wib = ws + OFF_WIB;
    const u16* Wih = ws + OFF_WIH;
    const u16* Whh = ws + OFF_WHH;
    const u16* Wo1 = ws + OFF_WO1;
    const u16* Wo2 = ws + OFF_WO2;

    bf16x8 wib[3];
    #pragma unroll
    for (int kc = 0; kc < 3; ++kc)
        wib[kc] = *reinterpret_cast<const bf16x8*>(Wib + o * 96 + kc * 32 + quad * 8);

    bf16x8 wrx[8], wzx[8], wnx[8], wrh[8], wzh[8], wnh[8], wo1[8], wo2[8];
    #pragma unroll
    for (int kc = 0; kc < 8; ++kc) {
        const int ko = kc * 32 + quad * 8;
        wrx[kc] = *reinterpret_cast<const bf16x8*>(Wih + (size_t)o * 256 + ko);
        wzx[kc] = *reinterpret_cast<const bf16x8*>(Wih + (size_t)(o + 256) * 256 + ko);
        wnx[kc] = *reinterpret_cast<const bf16x8*>(Wih + (size_t)(o + 512) * 256 + ko);
        wrh[kc] = *reinterpret_cast<const bf16x8*>(Whh + (size_t)o * 256 + ko);
        wzh[kc] = *reinterpret_cast<const bf16x8*>(Whh + (size_t)(o + 256) * 256 + ko);
        wnh[kc] = *reinterpret_cast<const bf16x8*>(Whh + (size_t)(o + 512) * 256 + ko);
        wo1[kc] = *reinterpret_cast<const bf16x8*>(Wo1 + (size_t)o * 256 + ko);
        wo2[kc] = *reinterpret_cast<const bf16x8*>(Wo2 + (size_t)o5 * 256 + ko);
    }

    // one-time zero of zb (cols 66..95 stay 0 forever; 0..65 rewritten per tile)
    for (int i = tid; i < 32 * SZ / 2; i += 1024)
        reinterpret_cast<u32*>(zb)[i] = 0u;
    __syncthreads();

    // ================= tile loop: 8 tiles of 32 rows =================
    #pragma unroll 1
    for (int t = 0; t < 8; ++t) {
        const int row0 = (blockIdx.x * 8 + t) * 32;

        // ---- cooperative staging: hid, z, act -> LDS (bf16) ----
        {
            const float* hp = hid + (size_t)(row0 + sr) * 256 + sc;
            float4 a = *reinterpret_cast<const float4*>(hp);
            float4 b = *reinterpret_cast<const float4*>(hp + 4);
            bf16x8 v;
            v[0] = (short)f2b(a.x); v[1] = (short)f2b(a.y);
            v[2] = (short)f2b(a.z); v[3] = (short)f2b(a.w);
            v[4] = (short)f2b(b.x); v[5] = (short)f2b(b.y);
            v[6] = (short)f2b(b.z); v[7] = (short)f2b(b.w);
            *reinterpret_cast<bf16x8*>(&hb[sr * SH + sc]) = v;
        }
        {
            const int r = tid >> 5, c = (tid & 31) * 2;   // 32 rows x 64 cols
            float2 zv = *reinterpret_cast<const float2*>(z + (size_t)(row0 + r) * 64 + c);
            u32 pack = (u32)f2b(zv.x) | ((u32)f2b(zv.y) << 16);
            *reinterpret_cast<u32*>(&zb[r * SZ + c]) = pack;
        }
        if (tid < 32) {
            float2 av = *reinterpret_cast<const float2*>(act + (size_t)(row0 + tid) * 2);
            u32 pack = (u32)f2b(av.x) | ((u32)f2b(av.y) << 16);
            *reinterpret_cast<u32*>(&zb[tid * SZ + 64]) = pack;
        }
        __syncthreads();

        // ---- stage A: x = relu(xin @ W_in^T + b_in) -> xbuf ----
        {
            f32x4 acc[2] = {ZERO4, ZERO4};
            #pragma unroll
            for (int kc = 0; kc < 3; ++kc) {
                #pragma unroll
                for (int mt = 0; mt < 2; ++mt) {
                    bf16x8 a = *reinterpret_cast<const bf16x8*>(
                        &zb[(mt * 16 + l16) * SZ + kc * 32 + quad * 8]);
                    acc[mt] = MFMA(a, wib[kc], acc[mt]);
                }
            }
            #pragma unroll
            for (int mt = 0; mt < 2; ++mt)
                #pragma unroll
                for (int i = 0; i < 4; ++i) {
                    const int rl = mt * 16 + quad * 4 + i;   // C/D layout row
                    xbuf[rl * SH + o] = f2b(fmaxf(acc[mt][i] + bin_, 0.f));
                }
        }
        __syncthreads();

        // ---- GRU gates ----
        {
            f32x4 aR[2]  = {ZERO4, ZERO4};
            f32x4 aZ[2]  = {ZERO4, ZERO4};
            f32x4 aNi[2] = {ZERO4, ZERO4};
            f32x4 aNh[2] = {ZERO4, ZERO4};
            #pragma unroll
            for (int kc = 0; kc < 8; ++kc) {
                const int ko = kc * 32 + quad * 8;
                #pragma unroll
                for (int mt = 0; mt < 2; ++mt) {
                    bf16x8 a = *reinterpret_cast<const bf16x8*>(&xbuf[(mt * 16 + l16) * SH + ko]);
                    aR[mt]  = MFMA(a, wrx[kc], aR[mt]);
                    aZ[mt]  = MFMA(a, wzx[kc], aZ[mt]);
                    aNi[mt] = MFMA(a, wnx[kc], aNi[mt]);
                }
            }
            #pragma unroll
            for (int kc = 0; kc < 8; ++kc) {
                const int ko = kc * 32 + quad * 8;
                #pragma unroll
                for (int mt = 0; mt < 2; ++mt) {
                    bf16x8 a = *reinterpret_cast<const bf16x8*>(&hb[(mt * 16 + l16) * SH + ko]);
                    aR[mt]  = MFMA(a, wrh[kc], aR[mt]);
                    aZ[mt]  = MFMA(a, wzh[kc], aZ[mt]);
                    aNh[mt] = MFMA(a, wnh[kc], aNh[mt]);
                }
            }
            #pragma unroll
            for (int mt = 0; mt < 2; ++mt)
                #pragma unroll
                for (int i = 0; i < 4; ++i) {
                    const int rl = mt * 16 + quad * 4 + i;
                    const float hv = b2f(hb[rl * SH + o]);
                    const float r  = sigm(aR[mt][i] + brb);
                    const float zg = sigm(aZ[mt][i] + bzb);
                    const float n  = tanh_(aNi[mt][i] + bni + r * (aNh[mt][i] + bnh));
                    const float hn = n + zg * (hv - n);    // (1-zg)*n + zg*h
                    hnew[rl * SH + o] = f2b(hn);
                }
        }
        __syncthreads();

        // ---- h_out store (coalesced fp32) ----
        {
            bf16x8 v = *reinterpret_cast<const bf16x8*>(&hnew[sr * SH + sc]);
            float4 f0, f1;
            f0.x = b2f((u16)v[0]); f0.y = b2f((u16)v[1]); f0.z = b2f((u16)v[2]); f0.w = b2f((u16)v[3]);
            f1.x = b2f((u16)v[4]); f1.y = b2f((u16)v[5]); f1.z = b2f((u16)v[6]); f1.w = b2f((u16)v[7]);
            float* dst = h_out + (size_t)(row0 + sr) * 256 + sc;
            *reinterpret_cast<float4*>(dst)     = f0;
            *reinterpret_cast<float4*>(dst + 4) = f1;
        }

        // ---- stage 4: y = relu(h_new @ W_o1^T + b_o1) -> ybuf ----
        {
            f32x4 acc[2] = {ZERO4, ZERO4};
            #pragma unroll
            for (int kc = 0; kc < 8; ++kc) {
                const int ko = kc * 32 + quad * 8;
                #pragma unroll
                for (int mt = 0; mt < 2; ++mt) {
                    bf16x8 a = *reinterpret_cast<const bf16x8*>(&hnew[(mt * 16 + l16) * SH + ko]);
                    acc[mt] = MFMA(a, wo1[kc], acc[mt]);
                }
            }
            #pragma unroll
            for (int mt = 0; mt < 2; ++mt)
                #pragma unroll
                for (int i = 0; i < 4; ++i) {
                    const int rl = mt * 16 + quad * 4 + i;
                    ybuf[rl * SH + o] = f2b(fmaxf(acc[mt][i] + bo1_, 0.f));
                }
        }
        __syncthreads();

        // ---- stage 5: z_next = y @ W_o2^T + b_o2 (waves 0..7) ----
        if (w < 8) {
            f32x4 acc = ZERO4;
            #pragma unroll
            for (int kc = 0; kc < 8; ++kc) {
                bf16x8 a = *reinterpret_cast<const bf16x8*>(
                    &ybuf[(mh * 16 + l16) * SH + kc * 32 + quad * 8]);
                acc = MFMA(a, wo2[kc], acc);
            }
            #pragma unroll
            for (int i = 0; i < 4; ++i) {
                const int rl = mh * 16 + quad * 4 + i;
                zn_out[(size_t)(row0 + rl) * 64 + o5] = acc[i] + bo2_;
            }
        }
        __syncthreads();   // protect LDS reuse by next tile's staging
    }
}

extern "C" void kernel_launch(void* const* d_in, const int* in_sizes, int n_in,
                              void* d_out, int out_size, void* d_ws, size_t ws_size,
                              hipStream_t stream) {
    const float* z    = (const float*)d_in[0];
    const float* act  = (const float*)d_in[1];
    const float* hid  = (const float*)d_in[2];
    const float* W_in = (const float*)d_in[3];
    const float* b_in = (const float*)d_in[4];
    const float* W_ih = (const float*)d_in[5];
    const float* W_hh = (const float*)d_in[6];
    const float* b_ih = (const float*)d_in[7];
    const float* b_hh = (const float*)d_in[8];
    const float* W_o1 = (const float*)d_in[9];
    const float* b_o1 = (const float*)d_in[10];
    const float* W_o2 = (const float*)d_in[11];
    const float* b_o2 = (const float*)d_in[12];

    u16* ws = (u16*)d_ws;

    float* zn_out = (float*)d_out;                      // [B, 64]
    float* h_out  = zn_out + (size_t)B_TOT * 64;        // [1, B, 256]

    prep_weights<<<dim3((WS_TOT + 255) / 256), dim3(256), 0, stream>>>(
        W_in, W_ih, W_hh, W_o1, W_o2, ws);

    ldm_fused<<<dim3(512), dim3(1024), 0, stream>>>(
        z, act, hid, b_in, b_ih, b_hh, b_o1, b_o2, ws, zn_out, h_out);
}